// Round 8
// baseline (183.907 us; speedup 1.0000x reference)
//
#include <hip/hip_runtime.h>

// ---------------------------------------------------------------------------
// DynamicEncoder via MFMA (gfx950, mfma_f32_16x16x32_bf16) — FUSED + PIPELINED.
//
// Round 8: (1) each block loops over 2 t-tiles; the NEXT tile's x gather is
// issued during the current tile's stage2 so HBM streams under MFMA (the
// once-per-block gather stall halves; CU-level HBM/MFMA overlap).
// (2) out store goes through LDS (ys reused as f32, stride 36) so global
// writes are 128B-aligned float4 runs — kills the 2x write amplification
// (R7: WRITE_SIZE 30.4 MB for a 14.7 MB output).
//
// Stage1: x (64, 2047(+1 zero), 100ch) -> y0 tile bf16 in LDS (80 rows).
// Stage2: y0 tile -> out fp32 (64, 112, 512). Halo recomputed per tile.
//
// Workspace (bytes):
//   A1  @ 0      : [7 g][15 k][64 lane][8] bf16 = 107520
//   A2  @ 107520 : [7 p][2 ks][15 k][64][8] bf16 = 215040
//   BF0 @ 322560 : 112 f32 ; BF1 @ 323008 : 112 f32
// ---------------------------------------------------------------------------

#define OFF_A2  107520u
#define OFF_BF0 322560u
#define OFF_BF1 323008u

typedef unsigned int uint32;
typedef __attribute__((ext_vector_type(8))) short bs8;
typedef __attribute__((ext_vector_type(4))) float f32x4;
union U8 { uint4 u; bs8 s; };

// ---- graph constants (verified rounds 1-7) ----
__constant__ int c_pool0_len[14] = {2,2,2,2,1,2,2,1,2,2,1,2,2,2};
__constant__ int c_pool0_mem[14][2] = {{0,3},{6,9},{1,4},{7,10},{2,2},{5,8},{11,14},{12,12},
                                       {15,17},{19,21},{13,13},{16,18},{20,22},{23,24}};
__constant__ unsigned c_nbm0[25] = {
 0x180000Fu,0x1800017u,0x1800027u,0x1800049u,0x92u,0x124u,0x248u,0x490u,
 0x3920u,0x240u,0x480u,0x7900u,0xB900u,0x13900u,0x4800u,0x29000u,
 0x52000u,0xA8000u,0x150000u,0x2A0000u,0x540000u,0x280000u,0x500000u,
 0x180000Fu,0x180000Fu
};
__constant__ int c_pool1_len[7] = {2,2,2,1,3,3,1};
__constant__ int c_pool1_mem[7][3] = {{0,1,1},{2,3,3},{4,5,5},{6,6,6},{7,8,9},{10,11,12},{13,13,13}};
__constant__ unsigned c_nbm1[14] = {
 0x2017u,0x2003u,0x201Du,0xCu,0x2035u,0x4F0u,0x4E0u,0x5E0u,
 0x380u,0x300u,0xCE0u,0x1C00u,0x1800u,0x2017u
};
__constant__ int c_g1p[7][2] = {{0,13},{1,3},{2,4},{5,6},{7,10},{8,11},{9,12}};
__constant__ int c_U1[7][8] = {
 {0,1,2,3,6,23,24,25},
 {3,4,6,7,9,10,25,25},
 {0,1,2,4,5,7,23,24},
 {2,5,8,11,12,13,14,25},
 {8,11,12,13,15,16,25,25},
 {12,13,15,16,17,18,19,20},
 {17,18,19,20,21,22,25,25}};
__constant__ int c_U2[7][8] = {
 {0,1,2,4,13,14,14,14},
 {0,2,3,4,13,14,14,14},
 {0,2,4,5,6,7,10,13},
 {5,6,7,10,14,14,14,14},
 {5,6,7,8,9,10,14,14},
 {5,6,7,10,11,12,14,14},
 {0,1,2,4,13,14,14,14}};
__constant__ unsigned c_pk1a[7] = {0xC0301000u,0xC8483018u,0xB8281000u,0x70604010u,
                                   0xC8786040u,0x98887860u,0xC8A89888u};
__constant__ unsigned c_pk1b[7] = {0xC8B81808u,0xC8503820u,0xC0382008u,0xC8685828u,
                                   0xC8806858u,0xA0908068u,0xC8B0A090u};
__constant__ unsigned c_pk2[7][2] = {
 {0x40201000u,0xE0E0E0D0u},{0x40302000u,0xE0E0E0D0u},{0x50402000u,0xD0A07060u},
 {0xA0706050u,0xE0E0E0E0u},{0x80706050u,0xE0E0A090u},{0xA0706050u,0xE0E0C0B0u},
 {0x40201000u,0xE0E0E0D0u}};

__device__ __forceinline__ uint32 f2bf(float v) {
  uint32 u = __float_as_uint(v);
  return (u + 0x7fffu + ((u >> 16) & 1u)) >> 16;   // RNE
}

// ---------------------------------------------------------------------------
// Prep: bake fused (mask x pool-mean) weights straight into A-fragment order.
// ---------------------------------------------------------------------------
__global__ void prep_fused_weights(const float* __restrict__ w0, const float* __restrict__ b0,
                                   const float* __restrict__ w1, const float* __restrict__ b1,
                                   char* __restrict__ wsb) {
  int t = blockIdx.x * blockDim.x + threadIdx.x;
  if (t < 6720) {                       // A1: [7 g][15 k][64 lane] uint4
    int lane = t & 63;
    int r = t >> 6;
    int k = r % 15, g = r / 15;
    int m = lane & 15, h = lane >> 4;
    int pool = (m < 8) ? c_g1p[g][0] : c_g1p[g][1];
    int c = m & 7;
    int L = c_pool0_len[pool];
    float inv = 1.f / (float)L;
    uint32 us[8];
#pragma unroll
    for (int j = 0; j < 8; ++j) {
      int node = c_U1[g][2 * h + (j >> 2)];
      int ci = j & 3;
      float v = 0.f;
      if (node < 25) {
        for (int jj = 0; jj < L; ++jj) {
          int mem = c_pool0_mem[pool][jj];
          if ((c_nbm0[mem] >> node) & 1u)
            v += w0[(mem * 8 + c) * 1500 + (node * 4 + ci) * 15 + k];
        }
        v *= inv;
      }
      us[j] = f2bf(v);
    }
    uint4 o = make_uint4(us[0] | (us[1] << 16), us[2] | (us[3] << 16),
                         us[4] | (us[5] << 16), us[6] | (us[7] << 16));
    reinterpret_cast<uint4*>(wsb)[t] = o;
  } else if (t < 6720 + 13440) {        // A2: [7 p][2 ks][15 k][64 lane] uint4
    int t2 = t - 6720;
    int lane = t2 & 63;
    int r = t2 >> 6;
    int k = r % 15;
    int r2 = r / 15;
    int ks = r2 & 1, p = r2 >> 1;
    int c = lane & 15, h = lane >> 4;
    int node = c_U2[p][ks * 4 + h];
    int L = c_pool1_len[p];
    float inv = 1.f / (float)L;
    uint32 us[8];
#pragma unroll
    for (int j = 0; j < 8; ++j) {
      float v = 0.f;
      if (node < 14) {
        for (int jj = 0; jj < L; ++jj) {
          int mem = c_pool1_mem[p][jj];
          if ((c_nbm1[mem] >> node) & 1u)
            v += w1[(mem * 16 + c) * 1680 + (node * 8 + j) * 15 + k];
        }
        v *= inv;
      }
      us[j] = f2bf(v);
    }
    uint4 o = make_uint4(us[0] | (us[1] << 16), us[2] | (us[3] << 16),
                         us[4] | (us[5] << 16), us[6] | (us[7] << 16));
    reinterpret_cast<uint4*>(wsb + OFF_A2)[t2] = o;
  } else if (t < 6720 + 13440 + 112) {  // BF0
    int p = t - (6720 + 13440);
    int i = p >> 3, c = p & 7;
    int L = c_pool0_len[i];
    float v = 0.f;
    for (int jj = 0; jj < L; ++jj) v += b0[c_pool0_mem[i][jj] * 8 + c];
    reinterpret_cast<float*>(wsb + OFF_BF0)[p] = v / (float)L;
  } else if (t < 6720 + 13440 + 224) {  // BF1
    int p = t - (6720 + 13440 + 112);
    int i = p >> 4, c = p & 15;
    int L = c_pool1_len[i];
    float v = 0.f;
    for (int jj = 0; jj < L; ++jj) v += b1[c_pool1_mem[i][jj] * 16 + c];
    reinterpret_cast<float*>(wsb + OFF_BF1)[p] = v / (float)L;
  }
}

// gather one 173-frame x tile into rg[10] (bounds-checked, zero-padded)
#define GATHER(T0VAL)                                                          \
  do {                                                                         \
    const int gg = 4 * (T0VAL) - 21;                                           \
    _Pragma("unroll")                                                          \
    for (int i = 0; i < 10; ++i) {                                             \
      rg[i] = make_float4(0.f, 0.f, 0.f, 0.f);                                 \
      int e = tid + i * 448;                                                   \
      if (e < 4325) {                                                          \
        int f = e / 25, q = e - f * 25;                                        \
        int gt = gg + f;                                                       \
        if ((unsigned)gt < 2047u)                                              \
          rg[i] = *reinterpret_cast<const float4*>(xb + gt * 100 + 4 * q);     \
      }                                                                        \
    }                                                                          \
  } while (0)

// ---------------------------------------------------------------------------
// Fused conv, 2 t-tiles per block. 448 thr = 7 waves.
// ---------------------------------------------------------------------------
__global__ __launch_bounds__(448, 4) void conv_fused(const float* __restrict__ x,
                                                     const char* __restrict__ wsb,
                                                     float* __restrict__ out) {
  __shared__ __align__(16) unsigned char xs[173 * 256];  // 44.3 KB, x tile
  __shared__ __align__(16) unsigned char ys[80 * 256];   // 20.0 KB, y0 tile / f32 out tile
  float* const ysf = reinterpret_cast<float*>(ys);
  const int tid = threadIdx.x;
  const int lane = tid & 63;
  const int g = tid >> 6;            // wave index = pool-pair (s1) = pool (s2)
  const int m16 = lane & 15, h = lane >> 4;
  const int b = blockIdx.y;
  const float* __restrict__ xb = x + (size_t)b * (2047 * 100);

  // wave-invariant constants
  const uint4* __restrict__ A1p = reinterpret_cast<const uint4*>(wsb) + g * 960 + lane;
  const uint4* __restrict__ A2p =
      reinterpret_cast<const uint4*>(wsb + OFF_A2) + g * 1920 + lane;
  const int pa = c_g1p[g][0], pb = c_g1p[g][1];
  const int chbase = (h < 2) ? (pa * 8 + 4 * h) : (pb * 8 + 4 * (h - 2));
  const float4 bv0 = *reinterpret_cast<const float4*>(wsb + OFF_BF0 + chbase * 4);
  const float4 bv1 = *reinterpret_cast<const float4*>(wsb + OFF_BF1 + (g * 16 + 4 * h) * 4);
  const uint32 offA = (c_pk1a[g] >> (8 * h)) & 255u;
  const uint32 offB = (c_pk1b[g] >> (8 * h)) & 255u;

  float4 rg[10];
  GATHER(blockIdx.x * 64);           // tile 0 prologue gather

  for (int it = 0; it < 2; ++it) {
    const int t0 = blockIdx.x * 64 + it * 32;
    const int f0y = 2 * t0 - 7;

    // ---- staging write: rg -> xs (convert + swizzle); zero pad-node unit ----
    for (int e = tid; e < 173; e += 448)
      *reinterpret_cast<uint2*>(xs + e * 256 + (200u ^ (((e >> 1) & 15) << 3))) =
          make_uint2(0u, 0u);
#pragma unroll
    for (int i = 0; i < 10; ++i) {
      int e = tid + i * 448;
      if (e < 4325) {
        int f = e / 25, q = e - f * 25;
        uint2 w = make_uint2(f2bf(rg[i].x) | (f2bf(rg[i].y) << 16),
                             f2bf(rg[i].z) | (f2bf(rg[i].w) << 16));
        *reinterpret_cast<uint2*>(xs + f * 256 + ((q * 8) ^ (((f >> 1) & 15) << 3))) = w;
      }
    }
    // A1 prefetch (after staging writes: keeps VGPR peak low)
    U8 aw[15];
#pragma unroll
    for (int k = 0; k < 15; ++k) aw[k].u = A1p[k * 64];
    __syncthreads();   // BAR1: xs ready (and prev iter's ysf reads done)

    // ---- stage1 MFMA: 15 taps x 5 nt (80 y0 rows) ----
    f32x4 acc1[5];
#pragma unroll
    for (int nt = 0; nt < 5; ++nt) acc1[nt] = (f32x4)0.f;
#pragma unroll
    for (int k = 0; k < 15; ++k) {
      const uint32 sw = (uint32)(((m16 + (k >> 1)) & 15) << 3);
      const uint32 a0 = offA ^ sw, a1o = offB ^ sw;
      const unsigned char* base = xs + (2 * m16 + k) * 256;
#pragma unroll
      for (int nt = 0; nt < 5; ++nt) {
        uint2 lo = *reinterpret_cast<const uint2*>(base + nt * 8192 + a0);
        uint2 hi = *reinterpret_cast<const uint2*>(base + nt * 8192 + a1o);
        U8 bfr; bfr.u = make_uint4(lo.x, lo.y, hi.x, hi.y);
        acc1[nt] = __builtin_amdgcn_mfma_f32_16x16x32_bf16(aw[k].s, bfr.s, acc1[nt], 0, 0, 0);
      }
    }

    // A2 ks=0 prefetch (reuses aw), hidden under epilogue1
#pragma unroll
    for (int k = 0; k < 15; ++k) aw[k].u = A2p[k * 64];

    // ---- epilogue1: bias+relu, pack bf16, masked write into ys ----
#pragma unroll
    for (int nt = 0; nt < 5; ++nt) {
      int row = nt * 16 + m16;
      int fy = f0y + row;
      float o0 = fmaxf(acc1[nt][0] + bv0.x, 0.f);
      float o1 = fmaxf(acc1[nt][1] + bv0.y, 0.f);
      float o2 = fmaxf(acc1[nt][2] + bv0.z, 0.f);
      float o3 = fmaxf(acc1[nt][3] + bv0.w, 0.f);
      uint2 wpk = make_uint2(f2bf(o0) | (f2bf(o1) << 16), f2bf(o2) | (f2bf(o3) << 16));
      if ((unsigned)fy >= 1024u) wpk = make_uint2(0u, 0u);   // y0 zero-pad
      *reinterpret_cast<uint2*>(ys + row * 256 +
          (((uint32)(chbase * 2)) ^ (((row >> 1) & 7) << 4))) = wpk;
    }
    for (int e = tid; e < 80; e += 448)   // zero pad-node unit of each ys row
      *reinterpret_cast<uint4*>(ys + e * 256 + (224u ^ (((e >> 1) & 7) << 4))) =
          make_uint4(0u, 0u, 0u, 0u);
    __syncthreads();   // BAR2: ys ready

    // ---- issue NEXT tile's gather: flies under stage2 (+out store) ----
    if (it == 0) GATHER(blockIdx.x * 64 + 32);

    // ---- stage2 MFMA: 2 K-steps x 15 taps x 2 nt ----
    f32x4 acc2[2];
    acc2[0] = (f32x4)0.f; acc2[1] = (f32x4)0.f;
    {
      const uint32 noff = (c_pk2[g][0] >> (8 * h)) & 255u;
#pragma unroll
      for (int k = 0; k < 15; ++k) {
        const uint32 sw = (uint32)(((m16 + (k >> 1)) & 7) << 4);
        const unsigned char* base = ys + 2 * m16 * 256 + (noff ^ sw);
        U8 b0f, b1f;
        b0f.u = *reinterpret_cast<const uint4*>(base + k * 256);
        b1f.u = *reinterpret_cast<const uint4*>(base + (k + 32) * 256);
        acc2[0] = __builtin_amdgcn_mfma_f32_16x16x32_bf16(aw[k].s, b0f.s, acc2[0], 0, 0, 0);
        acc2[1] = __builtin_amdgcn_mfma_f32_16x16x32_bf16(aw[k].s, b1f.s, acc2[1], 0, 0, 0);
      }
    }
#pragma unroll
    for (int k = 0; k < 15; ++k) aw[k].u = A2p[(15 + k) * 64];   // ks=1 half
    {
      const uint32 noff = (c_pk2[g][1] >> (8 * h)) & 255u;
#pragma unroll
      for (int k = 0; k < 15; ++k) {
        const uint32 sw = (uint32)(((m16 + (k >> 1)) & 7) << 4);
        const unsigned char* base = ys + 2 * m16 * 256 + (noff ^ sw);
        U8 b0f, b1f;
        b0f.u = *reinterpret_cast<const uint4*>(base + k * 256);
        b1f.u = *reinterpret_cast<const uint4*>(base + (k + 32) * 256);
        acc2[0] = __builtin_amdgcn_mfma_f32_16x16x32_bf16(aw[k].s, b0f.s, acc2[0], 0, 0, 0);
        acc2[1] = __builtin_amdgcn_mfma_f32_16x16x32_bf16(aw[k].s, b1f.s, acc2[1], 0, 0, 0);
      }
    }
    __syncthreads();   // BAR3: all ys reads done, region free for f32 out tile

    // ---- out tile -> LDS f32 (stride 36 floats), then coalesced store ----
#pragma unroll
    for (int nt = 0; nt < 2; ++nt) {
      int t = nt * 16 + m16;
      ysf[(g * 16 + 4 * h + 0) * 36 + t] = fmaxf(acc2[nt][0] + bv1.x, 0.f);
      ysf[(g * 16 + 4 * h + 1) * 36 + t] = fmaxf(acc2[nt][1] + bv1.y, 0.f);
      ysf[(g * 16 + 4 * h + 2) * 36 + t] = fmaxf(acc2[nt][2] + bv1.z, 0.f);
      ysf[(g * 16 + 4 * h + 3) * 36 + t] = fmaxf(acc2[nt][3] + bv1.w, 0.f);
    }
    __syncthreads();   // BAR4: f32 out tile ready
#pragma unroll
    for (int r = 0; r < 2; ++r) {
      int e = tid + r * 448;           // e < 896 = 112 ch x 8 chunks
      int ch = e >> 3, jj = e & 7;
      float4 v = *reinterpret_cast<const float4*>(ysf + ch * 36 + jj * 4);
      *reinterpret_cast<float4*>(out + ((size_t)b * 112 + ch) * 512 + t0 + jj * 4) = v;
    }
  }
}

extern "C" void kernel_launch(void* const* d_in, const int* in_sizes, int n_in,
                              void* d_out, int out_size, void* d_ws, size_t ws_size,
                              hipStream_t stream) {
  const float* x  = (const float*)d_in[0];
  const float* w0 = (const float*)d_in[1];
  const float* b0 = (const float*)d_in[2];
  const float* w1 = (const float*)d_in[3];
  const float* b1 = (const float*)d_in[4];
  char* wsb = (char*)d_ws;
  float* out = (float*)d_out;

  prep_fused_weights<<<80, 256, 0, stream>>>(w0, b0, w1, b1, wsb);
  conv_fused<<<dim3(8, 64), 448, 0, stream>>>(x, wsb, out);
}

// Round 9
// 61.969 us; speedup vs baseline: 2.9677x; 2.9677x over previous
//
#include <hip/hip_runtime.h>

// ---------------------------------------------------------------------------
// DynamicEncoder via MFMA (gfx950, mfma_f32_16x16x32_bf16) — FUSED, T=16.
//
// Round 9: revert R8's cross-tile prefetch (rg[] live across barriers =>
// compiler pins 64 VGPR and spills ~500MB to scratch). Instead: shrink the
// tile to 16 out-frames (LDS 40.2KB) so 3-4 blocks fit per CU; inter-block
// phase skew provides the HBM/MFMA overlap. Keep R8's LDS-staged out store
// (fixes 2x write amplification).
//
// Stage1: x (64, 2047(+1 zero), 100ch) -> y0 tile bf16 in LDS (48 rows).
// Stage2: y0 tile -> out fp32 (64, 112, 512). Halo recomputed per tile.
//
// Workspace (bytes):
//   A1  @ 0      : [7 g][15 k][64 lane][8] bf16 = 107520
//   A2  @ 107520 : [7 p][2 ks][15 k][64][8] bf16 = 215040
//   BF0 @ 322560 : 112 f32 ; BF1 @ 323008 : 112 f32
// ---------------------------------------------------------------------------

#define OFF_A2  107520u
#define OFF_BF0 322560u
#define OFF_BF1 323008u

typedef unsigned int uint32;
typedef __attribute__((ext_vector_type(8))) short bs8;
typedef __attribute__((ext_vector_type(4))) float f32x4;
union U8 { uint4 u; bs8 s; };

// ---- graph constants (verified rounds 1-8) ----
__constant__ int c_pool0_len[14] = {2,2,2,2,1,2,2,1,2,2,1,2,2,2};
__constant__ int c_pool0_mem[14][2] = {{0,3},{6,9},{1,4},{7,10},{2,2},{5,8},{11,14},{12,12},
                                       {15,17},{19,21},{13,13},{16,18},{20,22},{23,24}};
__constant__ unsigned c_nbm0[25] = {
 0x180000Fu,0x1800017u,0x1800027u,0x1800049u,0x92u,0x124u,0x248u,0x490u,
 0x3920u,0x240u,0x480u,0x7900u,0xB900u,0x13900u,0x4800u,0x29000u,
 0x52000u,0xA8000u,0x150000u,0x2A0000u,0x540000u,0x280000u,0x500000u,
 0x180000Fu,0x180000Fu
};
__constant__ int c_pool1_len[7] = {2,2,2,1,3,3,1};
__constant__ int c_pool1_mem[7][3] = {{0,1,1},{2,3,3},{4,5,5},{6,6,6},{7,8,9},{10,11,12},{13,13,13}};
__constant__ unsigned c_nbm1[14] = {
 0x2017u,0x2003u,0x201Du,0xCu,0x2035u,0x4F0u,0x4E0u,0x5E0u,
 0x380u,0x300u,0xCE0u,0x1C00u,0x1800u,0x2017u
};
__constant__ int c_g1p[7][2] = {{0,13},{1,3},{2,4},{5,6},{7,10},{8,11},{9,12}};
__constant__ int c_U1[7][8] = {
 {0,1,2,3,6,23,24,25},
 {3,4,6,7,9,10,25,25},
 {0,1,2,4,5,7,23,24},
 {2,5,8,11,12,13,14,25},
 {8,11,12,13,15,16,25,25},
 {12,13,15,16,17,18,19,20},
 {17,18,19,20,21,22,25,25}};
__constant__ int c_U2[7][8] = {
 {0,1,2,4,13,14,14,14},
 {0,2,3,4,13,14,14,14},
 {0,2,4,5,6,7,10,13},
 {5,6,7,10,14,14,14,14},
 {5,6,7,8,9,10,14,14},
 {5,6,7,10,11,12,14,14},
 {0,1,2,4,13,14,14,14}};
__constant__ unsigned c_pk1a[7] = {0xC0301000u,0xC8483018u,0xB8281000u,0x70604010u,
                                   0xC8786040u,0x98887860u,0xC8A89888u};
__constant__ unsigned c_pk1b[7] = {0xC8B81808u,0xC8503820u,0xC0382008u,0xC8685828u,
                                   0xC8806858u,0xA0908068u,0xC8B0A090u};
__constant__ unsigned c_pk2[7][2] = {
 {0x40201000u,0xE0E0E0D0u},{0x40302000u,0xE0E0E0D0u},{0x50402000u,0xD0A07060u},
 {0xA0706050u,0xE0E0E0E0u},{0x80706050u,0xE0E0A090u},{0xA0706050u,0xE0E0C0B0u},
 {0x40201000u,0xE0E0E0D0u}};

__device__ __forceinline__ uint32 f2bf(float v) {
  uint32 u = __float_as_uint(v);
  return (u + 0x7fffu + ((u >> 16) & 1u)) >> 16;   // RNE
}

// ---------------------------------------------------------------------------
// Prep: bake fused (mask x pool-mean) weights straight into A-fragment order.
// ---------------------------------------------------------------------------
__global__ void prep_fused_weights(const float* __restrict__ w0, const float* __restrict__ b0,
                                   const float* __restrict__ w1, const float* __restrict__ b1,
                                   char* __restrict__ wsb) {
  int t = blockIdx.x * blockDim.x + threadIdx.x;
  if (t < 6720) {                       // A1: [7 g][15 k][64 lane] uint4
    int lane = t & 63;
    int r = t >> 6;
    int k = r % 15, g = r / 15;
    int m = lane & 15, h = lane >> 4;
    int pool = (m < 8) ? c_g1p[g][0] : c_g1p[g][1];
    int c = m & 7;
    int L = c_pool0_len[pool];
    float inv = 1.f / (float)L;
    uint32 us[8];
#pragma unroll
    for (int j = 0; j < 8; ++j) {
      int node = c_U1[g][2 * h + (j >> 2)];
      int ci = j & 3;
      float v = 0.f;
      if (node < 25) {
        for (int jj = 0; jj < L; ++jj) {
          int mem = c_pool0_mem[pool][jj];
          if ((c_nbm0[mem] >> node) & 1u)
            v += w0[(mem * 8 + c) * 1500 + (node * 4 + ci) * 15 + k];
        }
        v *= inv;
      }
      us[j] = f2bf(v);
    }
    uint4 o = make_uint4(us[0] | (us[1] << 16), us[2] | (us[3] << 16),
                         us[4] | (us[5] << 16), us[6] | (us[7] << 16));
    reinterpret_cast<uint4*>(wsb)[t] = o;
  } else if (t < 6720 + 13440) {        // A2: [7 p][2 ks][15 k][64 lane] uint4
    int t2 = t - 6720;
    int lane = t2 & 63;
    int r = t2 >> 6;
    int k = r % 15;
    int r2 = r / 15;
    int ks = r2 & 1, p = r2 >> 1;
    int c = lane & 15, h = lane >> 4;
    int node = c_U2[p][ks * 4 + h];
    int L = c_pool1_len[p];
    float inv = 1.f / (float)L;
    uint32 us[8];
#pragma unroll
    for (int j = 0; j < 8; ++j) {
      float v = 0.f;
      if (node < 14) {
        for (int jj = 0; jj < L; ++jj) {
          int mem = c_pool1_mem[p][jj];
          if ((c_nbm1[mem] >> node) & 1u)
            v += w1[(mem * 16 + c) * 1680 + (node * 8 + j) * 15 + k];
        }
        v *= inv;
      }
      us[j] = f2bf(v);
    }
    uint4 o = make_uint4(us[0] | (us[1] << 16), us[2] | (us[3] << 16),
                         us[4] | (us[5] << 16), us[6] | (us[7] << 16));
    reinterpret_cast<uint4*>(wsb + OFF_A2)[t2] = o;
  } else if (t < 6720 + 13440 + 112) {  // BF0
    int p = t - (6720 + 13440);
    int i = p >> 3, c = p & 7;
    int L = c_pool0_len[i];
    float v = 0.f;
    for (int jj = 0; jj < L; ++jj) v += b0[c_pool0_mem[i][jj] * 8 + c];
    reinterpret_cast<float*>(wsb + OFF_BF0)[p] = v / (float)L;
  } else if (t < 6720 + 13440 + 224) {  // BF1
    int p = t - (6720 + 13440 + 112);
    int i = p >> 4, c = p & 15;
    int L = c_pool1_len[i];
    float v = 0.f;
    for (int jj = 0; jj < L; ++jj) v += b1[c_pool1_mem[i][jj] * 16 + c];
    reinterpret_cast<float*>(wsb + OFF_BF1)[p] = v / (float)L;
  }
}

// ---------------------------------------------------------------------------
// Fused conv, 16 out-frames per block. 448 thr = 7 waves (wave = pool-pair /
// pool). LDS: xs 109x256B (27.3KB) + ys 48x256B (12KB) = 40.2KB.
// ---------------------------------------------------------------------------
__global__ __launch_bounds__(448, 4) void conv_fused(const float* __restrict__ x,
                                                     const char* __restrict__ wsb,
                                                     float* __restrict__ out) {
  __shared__ __align__(16) unsigned char xs[109 * 256];  // x tile (bf16, swizzled)
  __shared__ __align__(16) unsigned char ys[48 * 256];   // y0 tile / f32 out tile
  float* const ysf = reinterpret_cast<float*>(ys);
  const int tid = threadIdx.x;
  const int lane = tid & 63;
  const int g = tid >> 6;            // wave index = pool-pair (s1) = pool (s2)
  const int m16 = lane & 15, h = lane >> 4;
  const int b = blockIdx.y;
  const int t0 = blockIdx.x << 4;    // 16 output frames per block
  const int f0y = 2 * t0 - 7;        // ys row r <-> y0 frame f0y + r
  const int g0x = 4 * t0 - 21;       // xs row f <-> x frame g0x + f
  const float* __restrict__ xb = x + (size_t)b * (2047 * 100);

  // ---- gather x tile (109 frames x 25 float4 = 2725): all loads in flight ----
  float4 rg[7];
#pragma unroll
  for (int i = 0; i < 7; ++i) {
    rg[i] = make_float4(0.f, 0.f, 0.f, 0.f);
    int e = tid + i * 448;
    if (e < 2725) {
      int f = e / 25, q = e - f * 25;
      int gt = g0x + f;
      if ((unsigned)gt < 2047u)
        rg[i] = *reinterpret_cast<const float4*>(xb + gt * 100 + 4 * q);
    }
  }
  // zero pad-node unit (bytes 200..207) of each x row
  for (int e = tid; e < 109; e += 448)
    *reinterpret_cast<uint2*>(xs + e * 256 + (200u ^ (((e >> 1) & 15) << 3))) =
        make_uint2(0u, 0u);
  // convert + swizzled ds_write
#pragma unroll
  for (int i = 0; i < 7; ++i) {
    int e = tid + i * 448;
    if (e < 2725) {
      int f = e / 25, q = e - f * 25;
      uint2 w = make_uint2(f2bf(rg[i].x) | (f2bf(rg[i].y) << 16),
                           f2bf(rg[i].z) | (f2bf(rg[i].w) << 16));
      *reinterpret_cast<uint2*>(xs + f * 256 + ((q * 8) ^ (((f >> 1) & 15) << 3))) = w;
    }
  }
  // A1 + bias prefetch (after staging writes: short live ranges, no spill)
  const uint4* __restrict__ A1p = reinterpret_cast<const uint4*>(wsb) + g * 960 + lane;
  U8 aw[15];
#pragma unroll
  for (int k = 0; k < 15; ++k) aw[k].u = A1p[k * 64];
  const int pa = c_g1p[g][0], pb = c_g1p[g][1];
  const int chbase = (h < 2) ? (pa * 8 + 4 * h) : (pb * 8 + 4 * (h - 2));
  const float4 bv0 = *reinterpret_cast<const float4*>(wsb + OFF_BF0 + chbase * 4);
  __syncthreads();   // BAR1: xs ready

  // ---- stage1 MFMA: 15 taps x 3 nt (48 y0 rows) ----
  const uint32 offA = (c_pk1a[g] >> (8 * h)) & 255u;
  const uint32 offB = (c_pk1b[g] >> (8 * h)) & 255u;
  f32x4 acc1[3];
#pragma unroll
  for (int nt = 0; nt < 3; ++nt) acc1[nt] = (f32x4)0.f;
#pragma unroll
  for (int k = 0; k < 15; ++k) {
    const uint32 sw = (uint32)(((m16 + (k >> 1)) & 15) << 3);
    const uint32 a0 = offA ^ sw, a1o = offB ^ sw;
    const unsigned char* base = xs + (2 * m16 + k) * 256;
#pragma unroll
    for (int nt = 0; nt < 3; ++nt) {
      uint2 lo = *reinterpret_cast<const uint2*>(base + nt * 8192 + a0);
      uint2 hi = *reinterpret_cast<const uint2*>(base + nt * 8192 + a1o);
      U8 bfr; bfr.u = make_uint4(lo.x, lo.y, hi.x, hi.y);
      acc1[nt] = __builtin_amdgcn_mfma_f32_16x16x32_bf16(aw[k].s, bfr.s, acc1[nt], 0, 0, 0);
    }
  }

  // A2 ks=0 prefetch (reuses aw) + stage2 bias, hidden under epilogue1
  const uint4* __restrict__ A2p =
      reinterpret_cast<const uint4*>(wsb + OFF_A2) + g * 1920 + lane;
#pragma unroll
  for (int k = 0; k < 15; ++k) aw[k].u = A2p[k * 64];
  const float4 bv1 = *reinterpret_cast<const float4*>(wsb + OFF_BF1 + (g * 16 + 4 * h) * 4);

  // ---- epilogue1: bias+relu, pack bf16, masked write into ys ----
#pragma unroll
  for (int nt = 0; nt < 3; ++nt) {
    int row = nt * 16 + m16;
    int fy = f0y + row;
    float o0 = fmaxf(acc1[nt][0] + bv0.x, 0.f);
    float o1 = fmaxf(acc1[nt][1] + bv0.y, 0.f);
    float o2 = fmaxf(acc1[nt][2] + bv0.z, 0.f);
    float o3 = fmaxf(acc1[nt][3] + bv0.w, 0.f);
    uint2 wpk = make_uint2(f2bf(o0) | (f2bf(o1) << 16), f2bf(o2) | (f2bf(o3) << 16));
    if ((unsigned)fy >= 1024u) wpk = make_uint2(0u, 0u);   // y0 zero-pad
    *reinterpret_cast<uint2*>(ys + row * 256 +
        (((uint32)(chbase * 2)) ^ (((row >> 1) & 7) << 4))) = wpk;
  }
  for (int e = tid; e < 48; e += 448)   // zero pad-node unit of each ys row
    *reinterpret_cast<uint4*>(ys + e * 256 + (224u ^ (((e >> 1) & 7) << 4))) =
        make_uint4(0u, 0u, 0u, 0u);
  __syncthreads();   // BAR2: ys ready

  // ---- stage2 MFMA: 2 K-steps x 15 taps, single 16-frame n-tile ----
  f32x4 acc2 = (f32x4)0.f;
  {
    const uint32 noff = (c_pk2[g][0] >> (8 * h)) & 255u;
#pragma unroll
    for (int k = 0; k < 15; ++k) {
      const uint32 sw = (uint32)(((m16 + (k >> 1)) & 7) << 4);
      U8 bf;
      bf.u = *reinterpret_cast<const uint4*>(ys + (2 * m16 + k) * 256 + (noff ^ sw));
      acc2 = __builtin_amdgcn_mfma_f32_16x16x32_bf16(aw[k].s, bf.s, acc2, 0, 0, 0);
    }
  }
#pragma unroll
  for (int k = 0; k < 15; ++k) aw[k].u = A2p[(15 + k) * 64];   // ks=1 half
  {
    const uint32 noff = (c_pk2[g][1] >> (8 * h)) & 255u;
#pragma unroll
    for (int k = 0; k < 15; ++k) {
      const uint32 sw = (uint32)(((m16 + (k >> 1)) & 7) << 4);
      U8 bf;
      bf.u = *reinterpret_cast<const uint4*>(ys + (2 * m16 + k) * 256 + (noff ^ sw));
      acc2 = __builtin_amdgcn_mfma_f32_16x16x32_bf16(aw[k].s, bf.s, acc2, 0, 0, 0);
    }
  }
  __syncthreads();   // BAR3: ys reads done, region free for f32 out tile

  // ---- out tile -> LDS f32 (stride 20 floats), then coalesced store ----
  {
    int t = m16;
    ysf[(g * 16 + 4 * h + 0) * 20 + t] = fmaxf(acc2[0] + bv1.x, 0.f);
    ysf[(g * 16 + 4 * h + 1) * 20 + t] = fmaxf(acc2[1] + bv1.y, 0.f);
    ysf[(g * 16 + 4 * h + 2) * 20 + t] = fmaxf(acc2[2] + bv1.z, 0.f);
    ysf[(g * 16 + 4 * h + 3) * 20 + t] = fmaxf(acc2[3] + bv1.w, 0.f);
  }
  __syncthreads();   // BAR4: f32 out tile ready
  {
    int ch = tid >> 2, jj = tid & 3;   // 448 = 112 ch x 4 chunks
    float4 v = *reinterpret_cast<const float4*>(ysf + ch * 20 + jj * 4);
    *reinterpret_cast<float4*>(out + ((size_t)b * 112 + ch) * 512 + t0 + jj * 4) = v;
  }
}

extern "C" void kernel_launch(void* const* d_in, const int* in_sizes, int n_in,
                              void* d_out, int out_size, void* d_ws, size_t ws_size,
                              hipStream_t stream) {
  const float* x  = (const float*)d_in[0];
  const float* w0 = (const float*)d_in[1];
  const float* b0 = (const float*)d_in[2];
  const float* w1 = (const float*)d_in[3];
  const float* b1 = (const float*)d_in[4];
  char* wsb = (char*)d_ws;
  float* out = (float*)d_out;

  prep_fused_weights<<<80, 256, 0, stream>>>(w0, b0, w1, b1, wsb);
  conv_fused<<<dim3(32, 64), 448, 0, stream>>>(x, wsb, out);
}

// Round 10
// 56.387 us; speedup vs baseline: 3.2615x; 1.0990x over previous
//
#include <hip/hip_runtime.h>

// ---------------------------------------------------------------------------
// DynamicEncoder via MFMA (gfx950, mfma_f32_16x16x32_bf16) — FUSED, T=32.
//
// Round 10: R7 base (proven 53.6us) + two proven fixes:
//  (a) out store staged through LDS as fp32 (stride 36) -> aligned float4
//      stores; kills the 2x write amplification (30.4MB -> ~15MB).
//  (b) removed the unnecessary barrier before epilogue1 (ys is disjoint from
//      xs and not yet read).
// Weight-L2 analysis (R7 vs R9): per-block A-table traffic = 315KB ~ 1/T, so
// T=32 (1024 blocks, 322MB L2) is the operating point; weight persistence in
// VGPRs (~180 regs) would break the <=128-VGPR 2-block residency. Stay <=128.
//
// Stage1: x (64, 2047(+1 zero), 100ch) -> y0 tile bf16 in LDS (80 rows).
// Stage2: y0 tile -> out fp32 (64, 112, 512). Halo recomputed per tile.
//
// Workspace (bytes):
//   A1  @ 0      : [7 g][15 k][64 lane][8] bf16 = 107520
//   A2  @ 107520 : [7 p][2 ks][15 k][64][8] bf16 = 215040
//   BF0 @ 322560 : 112 f32 ; BF1 @ 323008 : 112 f32
// ---------------------------------------------------------------------------

#define OFF_A2  107520u
#define OFF_BF0 322560u
#define OFF_BF1 323008u

typedef unsigned int uint32;
typedef __attribute__((ext_vector_type(8))) short bs8;
typedef __attribute__((ext_vector_type(4))) float f32x4;
union U8 { uint4 u; bs8 s; };

// ---- graph constants (verified rounds 1-9) ----
__constant__ int c_pool0_len[14] = {2,2,2,2,1,2,2,1,2,2,1,2,2,2};
__constant__ int c_pool0_mem[14][2] = {{0,3},{6,9},{1,4},{7,10},{2,2},{5,8},{11,14},{12,12},
                                       {15,17},{19,21},{13,13},{16,18},{20,22},{23,24}};
__constant__ unsigned c_nbm0[25] = {
 0x180000Fu,0x1800017u,0x1800027u,0x1800049u,0x92u,0x124u,0x248u,0x490u,
 0x3920u,0x240u,0x480u,0x7900u,0xB900u,0x13900u,0x4800u,0x29000u,
 0x52000u,0xA8000u,0x150000u,0x2A0000u,0x540000u,0x280000u,0x500000u,
 0x180000Fu,0x180000Fu
};
__constant__ int c_pool1_len[7] = {2,2,2,1,3,3,1};
__constant__ int c_pool1_mem[7][3] = {{0,1,1},{2,3,3},{4,5,5},{6,6,6},{7,8,9},{10,11,12},{13,13,13}};
__constant__ unsigned c_nbm1[14] = {
 0x2017u,0x2003u,0x201Du,0xCu,0x2035u,0x4F0u,0x4E0u,0x5E0u,
 0x380u,0x300u,0xCE0u,0x1C00u,0x1800u,0x2017u
};
__constant__ int c_g1p[7][2] = {{0,13},{1,3},{2,4},{5,6},{7,10},{8,11},{9,12}};
__constant__ int c_U1[7][8] = {
 {0,1,2,3,6,23,24,25},
 {3,4,6,7,9,10,25,25},
 {0,1,2,4,5,7,23,24},
 {2,5,8,11,12,13,14,25},
 {8,11,12,13,15,16,25,25},
 {12,13,15,16,17,18,19,20},
 {17,18,19,20,21,22,25,25}};
__constant__ int c_U2[7][8] = {
 {0,1,2,4,13,14,14,14},
 {0,2,3,4,13,14,14,14},
 {0,2,4,5,6,7,10,13},
 {5,6,7,10,14,14,14,14},
 {5,6,7,8,9,10,14,14},
 {5,6,7,10,11,12,14,14},
 {0,1,2,4,13,14,14,14}};
__constant__ unsigned c_pk1a[7] = {0xC0301000u,0xC8483018u,0xB8281000u,0x70604010u,
                                   0xC8786040u,0x98887860u,0xC8A89888u};
__constant__ unsigned c_pk1b[7] = {0xC8B81808u,0xC8503820u,0xC0382008u,0xC8685828u,
                                   0xC8806858u,0xA0908068u,0xC8B0A090u};
__constant__ unsigned c_pk2[7][2] = {
 {0x40201000u,0xE0E0E0D0u},{0x40302000u,0xE0E0E0D0u},{0x50402000u,0xD0A07060u},
 {0xA0706050u,0xE0E0E0E0u},{0x80706050u,0xE0E0A090u},{0xA0706050u,0xE0E0C0B0u},
 {0x40201000u,0xE0E0E0D0u}};

__device__ __forceinline__ uint32 f2bf(float v) {
  uint32 u = __float_as_uint(v);
  return (u + 0x7fffu + ((u >> 16) & 1u)) >> 16;   // RNE
}

// ---------------------------------------------------------------------------
// Prep: bake fused (mask x pool-mean) weights straight into A-fragment order.
// ---------------------------------------------------------------------------
__global__ void prep_fused_weights(const float* __restrict__ w0, const float* __restrict__ b0,
                                   const float* __restrict__ w1, const float* __restrict__ b1,
                                   char* __restrict__ wsb) {
  int t = blockIdx.x * blockDim.x + threadIdx.x;
  if (t < 6720) {                       // A1: [7 g][15 k][64 lane] uint4
    int lane = t & 63;
    int r = t >> 6;
    int k = r % 15, g = r / 15;
    int m = lane & 15, h = lane >> 4;
    int pool = (m < 8) ? c_g1p[g][0] : c_g1p[g][1];
    int c = m & 7;
    int L = c_pool0_len[pool];
    float inv = 1.f / (float)L;
    uint32 us[8];
#pragma unroll
    for (int j = 0; j < 8; ++j) {
      int node = c_U1[g][2 * h + (j >> 2)];
      int ci = j & 3;
      float v = 0.f;
      if (node < 25) {
        for (int jj = 0; jj < L; ++jj) {
          int mem = c_pool0_mem[pool][jj];
          if ((c_nbm0[mem] >> node) & 1u)
            v += w0[(mem * 8 + c) * 1500 + (node * 4 + ci) * 15 + k];
        }
        v *= inv;
      }
      us[j] = f2bf(v);
    }
    uint4 o = make_uint4(us[0] | (us[1] << 16), us[2] | (us[3] << 16),
                         us[4] | (us[5] << 16), us[6] | (us[7] << 16));
    reinterpret_cast<uint4*>(wsb)[t] = o;
  } else if (t < 6720 + 13440) {        // A2: [7 p][2 ks][15 k][64 lane] uint4
    int t2 = t - 6720;
    int lane = t2 & 63;
    int r = t2 >> 6;
    int k = r % 15;
    int r2 = r / 15;
    int ks = r2 & 1, p = r2 >> 1;
    int c = lane & 15, h = lane >> 4;
    int node = c_U2[p][ks * 4 + h];
    int L = c_pool1_len[p];
    float inv = 1.f / (float)L;
    uint32 us[8];
#pragma unroll
    for (int j = 0; j < 8; ++j) {
      float v = 0.f;
      if (node < 14) {
        for (int jj = 0; jj < L; ++jj) {
          int mem = c_pool1_mem[p][jj];
          if ((c_nbm1[mem] >> node) & 1u)
            v += w1[(mem * 16 + c) * 1680 + (node * 8 + j) * 15 + k];
        }
        v *= inv;
      }
      us[j] = f2bf(v);
    }
    uint4 o = make_uint4(us[0] | (us[1] << 16), us[2] | (us[3] << 16),
                         us[4] | (us[5] << 16), us[6] | (us[7] << 16));
    reinterpret_cast<uint4*>(wsb + OFF_A2)[t2] = o;
  } else if (t < 6720 + 13440 + 112) {  // BF0
    int p = t - (6720 + 13440);
    int i = p >> 3, c = p & 7;
    int L = c_pool0_len[i];
    float v = 0.f;
    for (int jj = 0; jj < L; ++jj) v += b0[c_pool0_mem[i][jj] * 8 + c];
    reinterpret_cast<float*>(wsb + OFF_BF0)[p] = v / (float)L;
  } else if (t < 6720 + 13440 + 224) {  // BF1
    int p = t - (6720 + 13440 + 112);
    int i = p >> 4, c = p & 15;
    int L = c_pool1_len[i];
    float v = 0.f;
    for (int jj = 0; jj < L; ++jj) v += b1[c_pool1_mem[i][jj] * 16 + c];
    reinterpret_cast<float*>(wsb + OFF_BF1)[p] = v / (float)L;
  }
}

// ---------------------------------------------------------------------------
// Fused conv: block = (32 out frames, batch). 448 thr = 7 waves.
// Wave g: stage1 pool-pair g (5 nt of 16 y0 rows), then stage2 pool g.
// ---------------------------------------------------------------------------
__global__ __launch_bounds__(448, 4) void conv_fused(const float* __restrict__ x,
                                                     const char* __restrict__ wsb,
                                                     float* __restrict__ out) {
  __shared__ __align__(16) unsigned char xs[173 * 256];  // 44.3 KB, x tile
  __shared__ __align__(16) unsigned char ys[80 * 256];   // 20.0 KB, y0 tile / f32 out tile
  float* const ysf = reinterpret_cast<float*>(ys);
  const int tid = threadIdx.x;
  const int lane = tid & 63;
  const int g = tid >> 6;            // wave index = pool-pair (s1) = pool (s2)
  const int m16 = lane & 15, h = lane >> 4;
  const int b = blockIdx.y;
  const int t0 = blockIdx.x << 5;    // 32 output frames per block
  const int f0y = 2 * t0 - 7;        // ys row r <-> y0 frame f0y + r
  const int g0x = 4 * t0 - 21;       // xs row f <-> x frame g0x + f

  // ---- gather x tile: issue ALL loads, then convert+swizzled ds_write ----
  const float* __restrict__ xb = x + (size_t)b * (2047 * 100);
  float4 rg[10];
#pragma unroll
  for (int i = 0; i < 10; ++i) {
    rg[i] = make_float4(0.f, 0.f, 0.f, 0.f);
    int e = tid + i * 448;
    if (e < 4325) {                       // 173 frames x 25 float4
      int f = e / 25, q = e - f * 25;
      int gt = g0x + f;
      if ((unsigned)gt < 2047u)
        rg[i] = *reinterpret_cast<const float4*>(xb + gt * 100 + 4 * q);
    }
  }
  // zero pad-node unit (bytes 200..207) of each x row
  for (int e = tid; e < 173; e += 448)
    *reinterpret_cast<uint2*>(xs + e * 256 + (200u ^ (((e >> 1) & 15) << 3))) =
        make_uint2(0u, 0u);
#pragma unroll
  for (int i = 0; i < 10; ++i) {
    int e = tid + i * 448;
    if (e < 4325) {
      int f = e / 25, q = e - f * 25;
      uint2 w = make_uint2(f2bf(rg[i].x) | (f2bf(rg[i].y) << 16),
                           f2bf(rg[i].z) | (f2bf(rg[i].w) << 16));
      *reinterpret_cast<uint2*>(xs + f * 256 + ((q * 8) ^ (((f >> 1) & 15) << 3))) = w;
    }
  }
  // A1 + bias prefetch (after staging writes: keeps peak VGPR < 128)
  const uint4* __restrict__ A1p = reinterpret_cast<const uint4*>(wsb) + g * 960 + lane;
  U8 aw[15];
#pragma unroll
  for (int k = 0; k < 15; ++k) aw[k].u = A1p[k * 64];
  const int pa = c_g1p[g][0], pb = c_g1p[g][1];
  const int chbase = (h < 2) ? (pa * 8 + 4 * h) : (pb * 8 + 4 * (h - 2));
  const float4 bv0 = *reinterpret_cast<const float4*>(wsb + OFF_BF0 + chbase * 4);
  __syncthreads();   // BAR1: xs ready

  // ---- stage1 MFMA: 15 taps x 5 nt (80 y0 rows) ----
  const uint32 offA = (c_pk1a[g] >> (8 * h)) & 255u;
  const uint32 offB = (c_pk1b[g] >> (8 * h)) & 255u;
  f32x4 acc1[5];
#pragma unroll
  for (int nt = 0; nt < 5; ++nt) acc1[nt] = (f32x4)0.f;
#pragma unroll
  for (int k = 0; k < 15; ++k) {
    const uint32 sw = (uint32)(((m16 + (k >> 1)) & 15) << 3);
    const uint32 a0 = offA ^ sw, a1o = offB ^ sw;
    const unsigned char* base = xs + (2 * m16 + k) * 256;
#pragma unroll
    for (int nt = 0; nt < 5; ++nt) {
      uint2 lo = *reinterpret_cast<const uint2*>(base + nt * 8192 + a0);
      uint2 hi = *reinterpret_cast<const uint2*>(base + nt * 8192 + a1o);
      U8 bfr; bfr.u = make_uint4(lo.x, lo.y, hi.x, hi.y);
      acc1[nt] = __builtin_amdgcn_mfma_f32_16x16x32_bf16(aw[k].s, bfr.s, acc1[nt], 0, 0, 0);
    }
  }

  // prefetch A2 ks=0 half (reuses aw regs) + stage2 bias, hidden by epilogue
  const uint4* __restrict__ A2p =
      reinterpret_cast<const uint4*>(wsb + OFF_A2) + g * 1920 + lane;
#pragma unroll
  for (int k = 0; k < 15; ++k) aw[k].u = A2p[k * 64];
  const float4 bv1 = *reinterpret_cast<const float4*>(wsb + OFF_BF1 + (g * 16 + 4 * h) * 4);

  // ---- epilogue1: bias+relu, pack bf16, masked write into ys ----
  // (no barrier needed: ys disjoint from xs, not yet read by anyone)
#pragma unroll
  for (int nt = 0; nt < 5; ++nt) {
    int row = nt * 16 + m16;
    int fy = f0y + row;
    float o0 = fmaxf(acc1[nt][0] + bv0.x, 0.f);
    float o1 = fmaxf(acc1[nt][1] + bv0.y, 0.f);
    float o2 = fmaxf(acc1[nt][2] + bv0.z, 0.f);
    float o3 = fmaxf(acc1[nt][3] + bv0.w, 0.f);
    uint2 wpk = make_uint2(f2bf(o0) | (f2bf(o1) << 16), f2bf(o2) | (f2bf(o3) << 16));
    if ((unsigned)fy >= 1024u) wpk = make_uint2(0u, 0u);   // y0 zero-pad
    *reinterpret_cast<uint2*>(ys + row * 256 +
        (((uint32)(chbase * 2)) ^ (((row >> 1) & 7) << 4))) = wpk;
  }
  for (int e = tid; e < 80; e += 448)   // zero pad-node unit of each ys row
    *reinterpret_cast<uint4*>(ys + e * 256 + (224u ^ (((e >> 1) & 7) << 4))) =
        make_uint4(0u, 0u, 0u, 0u);
  __syncthreads();   // BAR2: ys ready

  // ---- stage2 MFMA: 2 K-steps x 15 taps x 2 nt ----
  f32x4 acc2[2];
  acc2[0] = (f32x4)0.f; acc2[1] = (f32x4)0.f;
  {
    const uint32 noff = (c_pk2[g][0] >> (8 * h)) & 255u;
#pragma unroll
    for (int k = 0; k < 15; ++k) {
      const uint32 sw = (uint32)(((m16 + (k >> 1)) & 7) << 4);
      const unsigned char* base = ys + 2 * m16 * 256 + (noff ^ sw);
      U8 b0f, b1f;
      b0f.u = *reinterpret_cast<const uint4*>(base + k * 256);
      b1f.u = *reinterpret_cast<const uint4*>(base + (k + 32) * 256);
      acc2[0] = __builtin_amdgcn_mfma_f32_16x16x32_bf16(aw[k].s, b0f.s, acc2[0], 0, 0, 0);
      acc2[1] = __builtin_amdgcn_mfma_f32_16x16x32_bf16(aw[k].s, b1f.s, acc2[1], 0, 0, 0);
    }
  }
#pragma unroll
  for (int k = 0; k < 15; ++k) aw[k].u = A2p[(15 + k) * 64];   // ks=1 half
  {
    const uint32 noff = (c_pk2[g][1] >> (8 * h)) & 255u;
#pragma unroll
    for (int k = 0; k < 15; ++k) {
      const uint32 sw = (uint32)(((m16 + (k >> 1)) & 7) << 4);
      const unsigned char* base = ys + 2 * m16 * 256 + (noff ^ sw);
      U8 b0f, b1f;
      b0f.u = *reinterpret_cast<const uint4*>(base + k * 256);
      b1f.u = *reinterpret_cast<const uint4*>(base + (k + 32) * 256);
      acc2[0] = __builtin_amdgcn_mfma_f32_16x16x32_bf16(aw[k].s, b0f.s, acc2[0], 0, 0, 0);
      acc2[1] = __builtin_amdgcn_mfma_f32_16x16x32_bf16(aw[k].s, b1f.s, acc2[1], 0, 0, 0);
    }
  }
  __syncthreads();   // BAR3: ys reads done, region free for f32 out tile

  // ---- out tile -> LDS f32 (stride 36 floats), then coalesced store ----
#pragma unroll
  for (int nt = 0; nt < 2; ++nt) {
    int t = nt * 16 + m16;
    ysf[(g * 16 + 4 * h + 0) * 36 + t] = fmaxf(acc2[nt][0] + bv1.x, 0.f);
    ysf[(g * 16 + 4 * h + 1) * 36 + t] = fmaxf(acc2[nt][1] + bv1.y, 0.f);
    ysf[(g * 16 + 4 * h + 2) * 36 + t] = fmaxf(acc2[nt][2] + bv1.z, 0.f);
    ysf[(g * 16 + 4 * h + 3) * 36 + t] = fmaxf(acc2[nt][3] + bv1.w, 0.f);
  }
  __syncthreads();   // BAR4: f32 out tile ready
#pragma unroll
  for (int r = 0; r < 2; ++r) {
    int e = tid + r * 448;             // e < 896 = 112 ch x 8 chunks
    int ch = e >> 3, jj = e & 7;
    float4 v = *reinterpret_cast<const float4*>(ysf + ch * 36 + jj * 4);
    *reinterpret_cast<float4*>(out + ((size_t)b * 112 + ch) * 512 + t0 + jj * 4) = v;
  }
}

extern "C" void kernel_launch(void* const* d_in, const int* in_sizes, int n_in,
                              void* d_out, int out_size, void* d_ws, size_t ws_size,
                              hipStream_t stream) {
  const float* x  = (const float*)d_in[0];
  const float* w0 = (const float*)d_in[1];
  const float* b0 = (const float*)d_in[2];
  const float* w1 = (const float*)d_in[3];
  const float* b1 = (const float*)d_in[4];
  char* wsb = (char*)d_ws;
  float* out = (float*)d_out;

  prep_fused_weights<<<80, 256, 0, stream>>>(w0, b0, w1, b1, wsb);
  conv_fused<<<dim3(16, 64), 448, 0, stream>>>(x, wsb, out);
}

// Round 11
// 54.401 us; speedup vs baseline: 3.3806x; 1.0365x over previous
//
#include <hip/hip_runtime.h>

// ---------------------------------------------------------------------------
// DynamicEncoder via MFMA (gfx950, mfma_f32_16x16x32_bf16) — FUSED, T=32,
// LDS OVERLAY.
//
// Round 11: revert R10's store staging (WRITE_SIZE counter showed no
// improvement; 2 extra barriers cost 2.7us). Single change vs R7 (53.7us):
// ys ALIASES xs rows 0..79 — xs is dead after the pre-epilogue barrier
// (stage2 reads only ys), so LDS = 44.3KB -> 3 blocks/CU (21 waves/CU,
// +50% resident waves; R7 occupancy was 31% @ 2 blocks). Same 3 barriers.
//
// Stage1: x (64, 2047(+1 zero), 100ch) -> y0 tile bf16 in LDS (80 rows).
// Stage2: y0 tile -> out fp32 (64, 112, 512). Halo recomputed per tile.
//
// Workspace (bytes):
//   A1  @ 0      : [7 g][15 k][64 lane][8] bf16 = 107520
//   A2  @ 107520 : [7 p][2 ks][15 k][64][8] bf16 = 215040
//   BF0 @ 322560 : 112 f32 ; BF1 @ 323008 : 112 f32
// ---------------------------------------------------------------------------

#define OFF_A2  107520u
#define OFF_BF0 322560u
#define OFF_BF1 323008u

typedef unsigned int uint32;
typedef __attribute__((ext_vector_type(8))) short bs8;
typedef __attribute__((ext_vector_type(4))) float f32x4;
union U8 { uint4 u; bs8 s; };

// ---- graph constants (verified rounds 1-10) ----
__constant__ int c_pool0_len[14] = {2,2,2,2,1,2,2,1,2,2,1,2,2,2};
__constant__ int c_pool0_mem[14][2] = {{0,3},{6,9},{1,4},{7,10},{2,2},{5,8},{11,14},{12,12},
                                       {15,17},{19,21},{13,13},{16,18},{20,22},{23,24}};
__constant__ unsigned c_nbm0[25] = {
 0x180000Fu,0x1800017u,0x1800027u,0x1800049u,0x92u,0x124u,0x248u,0x490u,
 0x3920u,0x240u,0x480u,0x7900u,0xB900u,0x13900u,0x4800u,0x29000u,
 0x52000u,0xA8000u,0x150000u,0x2A0000u,0x540000u,0x280000u,0x500000u,
 0x180000Fu,0x180000Fu
};
__constant__ int c_pool1_len[7] = {2,2,2,1,3,3,1};
__constant__ int c_pool1_mem[7][3] = {{0,1,1},{2,3,3},{4,5,5},{6,6,6},{7,8,9},{10,11,12},{13,13,13}};
__constant__ unsigned c_nbm1[14] = {
 0x2017u,0x2003u,0x201Du,0xCu,0x2035u,0x4F0u,0x4E0u,0x5E0u,
 0x380u,0x300u,0xCE0u,0x1C00u,0x1800u,0x2017u
};
__constant__ int c_g1p[7][2] = {{0,13},{1,3},{2,4},{5,6},{7,10},{8,11},{9,12}};
__constant__ int c_U1[7][8] = {
 {0,1,2,3,6,23,24,25},
 {3,4,6,7,9,10,25,25},
 {0,1,2,4,5,7,23,24},
 {2,5,8,11,12,13,14,25},
 {8,11,12,13,15,16,25,25},
 {12,13,15,16,17,18,19,20},
 {17,18,19,20,21,22,25,25}};
__constant__ int c_U2[7][8] = {
 {0,1,2,4,13,14,14,14},
 {0,2,3,4,13,14,14,14},
 {0,2,4,5,6,7,10,13},
 {5,6,7,10,14,14,14,14},
 {5,6,7,8,9,10,14,14},
 {5,6,7,10,11,12,14,14},
 {0,1,2,4,13,14,14,14}};
__constant__ unsigned c_pk1a[7] = {0xC0301000u,0xC8483018u,0xB8281000u,0x70604010u,
                                   0xC8786040u,0x98887860u,0xC8A89888u};
__constant__ unsigned c_pk1b[7] = {0xC8B81808u,0xC8503820u,0xC0382008u,0xC8685828u,
                                   0xC8806858u,0xA0908068u,0xC8B0A090u};
__constant__ unsigned c_pk2[7][2] = {
 {0x40201000u,0xE0E0E0D0u},{0x40302000u,0xE0E0E0D0u},{0x50402000u,0xD0A07060u},
 {0xA0706050u,0xE0E0E0E0u},{0x80706050u,0xE0E0A090u},{0xA0706050u,0xE0E0C0B0u},
 {0x40201000u,0xE0E0E0D0u}};

__device__ __forceinline__ uint32 f2bf(float v) {
  uint32 u = __float_as_uint(v);
  return (u + 0x7fffu + ((u >> 16) & 1u)) >> 16;   // RNE
}

// ---------------------------------------------------------------------------
// Prep: bake fused (mask x pool-mean) weights straight into A-fragment order.
// ---------------------------------------------------------------------------
__global__ void prep_fused_weights(const float* __restrict__ w0, const float* __restrict__ b0,
                                   const float* __restrict__ w1, const float* __restrict__ b1,
                                   char* __restrict__ wsb) {
  int t = blockIdx.x * blockDim.x + threadIdx.x;
  if (t < 6720) {                       // A1: [7 g][15 k][64 lane] uint4
    int lane = t & 63;
    int r = t >> 6;
    int k = r % 15, g = r / 15;
    int m = lane & 15, h = lane >> 4;
    int pool = (m < 8) ? c_g1p[g][0] : c_g1p[g][1];
    int c = m & 7;
    int L = c_pool0_len[pool];
    float inv = 1.f / (float)L;
    uint32 us[8];
#pragma unroll
    for (int j = 0; j < 8; ++j) {
      int node = c_U1[g][2 * h + (j >> 2)];
      int ci = j & 3;
      float v = 0.f;
      if (node < 25) {
        for (int jj = 0; jj < L; ++jj) {
          int mem = c_pool0_mem[pool][jj];
          if ((c_nbm0[mem] >> node) & 1u)
            v += w0[(mem * 8 + c) * 1500 + (node * 4 + ci) * 15 + k];
        }
        v *= inv;
      }
      us[j] = f2bf(v);
    }
    uint4 o = make_uint4(us[0] | (us[1] << 16), us[2] | (us[3] << 16),
                         us[4] | (us[5] << 16), us[6] | (us[7] << 16));
    reinterpret_cast<uint4*>(wsb)[t] = o;
  } else if (t < 6720 + 13440) {        // A2: [7 p][2 ks][15 k][64 lane] uint4
    int t2 = t - 6720;
    int lane = t2 & 63;
    int r = t2 >> 6;
    int k = r % 15;
    int r2 = r / 15;
    int ks = r2 & 1, p = r2 >> 1;
    int c = lane & 15, h = lane >> 4;
    int node = c_U2[p][ks * 4 + h];
    int L = c_pool1_len[p];
    float inv = 1.f / (float)L;
    uint32 us[8];
#pragma unroll
    for (int j = 0; j < 8; ++j) {
      float v = 0.f;
      if (node < 14) {
        for (int jj = 0; jj < L; ++jj) {
          int mem = c_pool1_mem[p][jj];
          if ((c_nbm1[mem] >> node) & 1u)
            v += w1[(mem * 16 + c) * 1680 + (node * 8 + j) * 15 + k];
        }
        v *= inv;
      }
      us[j] = f2bf(v);
    }
    uint4 o = make_uint4(us[0] | (us[1] << 16), us[2] | (us[3] << 16),
                         us[4] | (us[5] << 16), us[6] | (us[7] << 16));
    reinterpret_cast<uint4*>(wsb + OFF_A2)[t2] = o;
  } else if (t < 6720 + 13440 + 112) {  // BF0
    int p = t - (6720 + 13440);
    int i = p >> 3, c = p & 7;
    int L = c_pool0_len[i];
    float v = 0.f;
    for (int jj = 0; jj < L; ++jj) v += b0[c_pool0_mem[i][jj] * 8 + c];
    reinterpret_cast<float*>(wsb + OFF_BF0)[p] = v / (float)L;
  } else if (t < 6720 + 13440 + 224) {  // BF1
    int p = t - (6720 + 13440 + 112);
    int i = p >> 4, c = p & 15;
    int L = c_pool1_len[i];
    float v = 0.f;
    for (int jj = 0; jj < L; ++jj) v += b1[c_pool1_mem[i][jj] * 16 + c];
    reinterpret_cast<float*>(wsb + OFF_BF1)[p] = v / (float)L;
  }
}

// ---------------------------------------------------------------------------
// Fused conv: block = (32 out frames, batch). 448 thr = 7 waves.
// Wave g: stage1 pool-pair g (5 nt of 16 y0 rows), then stage2 pool g.
// LDS: single 44.3KB buffer; ys overlays rows 0..79 after stage1 completes.
// ---------------------------------------------------------------------------
__global__ __launch_bounds__(448, 4) void conv_fused(const float* __restrict__ x,
                                                     const char* __restrict__ wsb,
                                                     float* __restrict__ out) {
  __shared__ __align__(16) unsigned char lds[173 * 256];  // 44.3 KB (xs; ys aliases rows 0..79)
  unsigned char* const xs = lds;
  unsigned char* const ys = lds;
  const int tid = threadIdx.x;
  const int lane = tid & 63;
  const int g = tid >> 6;            // wave index = pool-pair (s1) = pool (s2)
  const int m16 = lane & 15, h = lane >> 4;
  const int b = blockIdx.y;
  const int t0 = blockIdx.x << 5;    // 32 output frames per block
  const int f0y = 2 * t0 - 7;        // ys row r <-> y0 frame f0y + r
  const int g0x = 4 * t0 - 21;       // xs row f <-> x frame g0x + f

  // ---- gather x tile: issue ALL loads, then convert+swizzled ds_write ----
  const float* __restrict__ xb = x + (size_t)b * (2047 * 100);
  float4 rg[10];
#pragma unroll
  for (int i = 0; i < 10; ++i) {
    rg[i] = make_float4(0.f, 0.f, 0.f, 0.f);
    int e = tid + i * 448;
    if (e < 4325) {                       // 173 frames x 25 float4
      int f = e / 25, q = e - f * 25;
      int gt = g0x + f;
      if ((unsigned)gt < 2047u)
        rg[i] = *reinterpret_cast<const float4*>(xb + gt * 100 + 4 * q);
    }
  }
  // zero pad-node unit (bytes 200..207) of each x row
  for (int e = tid; e < 173; e += 448)
    *reinterpret_cast<uint2*>(xs + e * 256 + (200u ^ (((e >> 1) & 15) << 3))) =
        make_uint2(0u, 0u);
#pragma unroll
  for (int i = 0; i < 10; ++i) {
    int e = tid + i * 448;
    if (e < 4325) {
      int f = e / 25, q = e - f * 25;
      uint2 w = make_uint2(f2bf(rg[i].x) | (f2bf(rg[i].y) << 16),
                           f2bf(rg[i].z) | (f2bf(rg[i].w) << 16));
      *reinterpret_cast<uint2*>(xs + f * 256 + ((q * 8) ^ (((f >> 1) & 15) << 3))) = w;
    }
  }
  // A1 + bias prefetch (after staging writes: keeps peak VGPR < 128)
  const uint4* __restrict__ A1p = reinterpret_cast<const uint4*>(wsb) + g * 960 + lane;
  U8 aw[15];
#pragma unroll
  for (int k = 0; k < 15; ++k) aw[k].u = A1p[k * 64];
  const int pa = c_g1p[g][0], pb = c_g1p[g][1];
  const int chbase = (h < 2) ? (pa * 8 + 4 * h) : (pb * 8 + 4 * (h - 2));
  const float4 bv0 = *reinterpret_cast<const float4*>(wsb + OFF_BF0 + chbase * 4);
  __syncthreads();   // BAR1: xs ready

  // ---- stage1 MFMA: 15 taps x 5 nt (80 y0 rows) ----
  const uint32 offA = (c_pk1a[g] >> (8 * h)) & 255u;
  const uint32 offB = (c_pk1b[g] >> (8 * h)) & 255u;
  f32x4 acc1[5];
#pragma unroll
  for (int nt = 0; nt < 5; ++nt) acc1[nt] = (f32x4)0.f;
#pragma unroll
  for (int k = 0; k < 15; ++k) {
    const uint32 sw = (uint32)(((m16 + (k >> 1)) & 15) << 3);
    const uint32 a0 = offA ^ sw, a1o = offB ^ sw;
    const unsigned char* base = xs + (2 * m16 + k) * 256;
#pragma unroll
    for (int nt = 0; nt < 5; ++nt) {
      uint2 lo = *reinterpret_cast<const uint2*>(base + nt * 8192 + a0);
      uint2 hi = *reinterpret_cast<const uint2*>(base + nt * 8192 + a1o);
      U8 bfr; bfr.u = make_uint4(lo.x, lo.y, hi.x, hi.y);
      acc1[nt] = __builtin_amdgcn_mfma_f32_16x16x32_bf16(aw[k].s, bfr.s, acc1[nt], 0, 0, 0);
    }
  }

  // prefetch A2 ks=0 half (reuses aw regs) + stage2 bias
  const uint4* __restrict__ A2p =
      reinterpret_cast<const uint4*>(wsb + OFF_A2) + g * 1920 + lane;
#pragma unroll
  for (int k = 0; k < 15; ++k) aw[k].u = A2p[k * 64];
  const float4 bv1 = *reinterpret_cast<const float4*>(wsb + OFF_BF1 + (g * 16 + 4 * h) * 4);
  __syncthreads();   // BAR_E: all xs reads done; rows 0..79 may be overwritten

  // ---- epilogue1: bias+relu, pack bf16, masked write into ys (= xs alias) ----
#pragma unroll
  for (int nt = 0; nt < 5; ++nt) {
    int row = nt * 16 + m16;
    int fy = f0y + row;
    float o0 = fmaxf(acc1[nt][0] + bv0.x, 0.f);
    float o1 = fmaxf(acc1[nt][1] + bv0.y, 0.f);
    float o2 = fmaxf(acc1[nt][2] + bv0.z, 0.f);
    float o3 = fmaxf(acc1[nt][3] + bv0.w, 0.f);
    uint2 wpk = make_uint2(f2bf(o0) | (f2bf(o1) << 16), f2bf(o2) | (f2bf(o3) << 16));
    if ((unsigned)fy >= 1024u) wpk = make_uint2(0u, 0u);   // y0 zero-pad
    *reinterpret_cast<uint2*>(ys + row * 256 +
        (((uint32)(chbase * 2)) ^ (((row >> 1) & 7) << 4))) = wpk;
  }
  for (int e = tid; e < 80; e += 448)   // zero pad-node unit of each ys row
    *reinterpret_cast<uint4*>(ys + e * 256 + (224u ^ (((e >> 1) & 7) << 4))) =
        make_uint4(0u, 0u, 0u, 0u);
  __syncthreads();   // BAR2: ys ready

  // ---- stage2 MFMA: 2 K-steps x 15 taps x 2 nt ----
  f32x4 acc2[2];
  acc2[0] = (f32x4)0.f; acc2[1] = (f32x4)0.f;
  {
    const uint32 noff = (c_pk2[g][0] >> (8 * h)) & 255u;
#pragma unroll
    for (int k = 0; k < 15; ++k) {
      const uint32 sw = (uint32)(((m16 + (k >> 1)) & 7) << 4);
      const unsigned char* base = ys + 2 * m16 * 256 + (noff ^ sw);
      U8 b0f, b1f;
      b0f.u = *reinterpret_cast<const uint4*>(base + k * 256);
      b1f.u = *reinterpret_cast<const uint4*>(base + (k + 32) * 256);
      acc2[0] = __builtin_amdgcn_mfma_f32_16x16x32_bf16(aw[k].s, b0f.s, acc2[0], 0, 0, 0);
      acc2[1] = __builtin_amdgcn_mfma_f32_16x16x32_bf16(aw[k].s, b1f.s, acc2[1], 0, 0, 0);
    }
  }
#pragma unroll
  for (int k = 0; k < 15; ++k) aw[k].u = A2p[(15 + k) * 64];   // ks=1 half
  {
    const uint32 noff = (c_pk2[g][1] >> (8 * h)) & 255u;
#pragma unroll
    for (int k = 0; k < 15; ++k) {
      const uint32 sw = (uint32)(((m16 + (k >> 1)) & 7) << 4);
      const unsigned char* base = ys + 2 * m16 * 256 + (noff ^ sw);
      U8 b0f, b1f;
      b0f.u = *reinterpret_cast<const uint4*>(base + k * 256);
      b1f.u = *reinterpret_cast<const uint4*>(base + (k + 32) * 256);
      acc2[0] = __builtin_amdgcn_mfma_f32_16x16x32_bf16(aw[k].s, b0f.s, acc2[0], 0, 0, 0);
      acc2[1] = __builtin_amdgcn_mfma_f32_16x16x32_bf16(aw[k].s, b1f.s, acc2[1], 0, 0, 0);
    }
  }

  // ---- out store (fp32, direct — R7 form) ----
#pragma unroll
  for (int nt = 0; nt < 2; ++nt) {
    size_t obase = ((size_t)b * 112 + g * 16 + 4 * h) * 512 + t0 + nt * 16 + m16;
    out[obase]        = fmaxf(acc2[nt][0] + bv1.x, 0.f);
    out[obase + 512]  = fmaxf(acc2[nt][1] + bv1.y, 0.f);
    out[obase + 1024] = fmaxf(acc2[nt][2] + bv1.z, 0.f);
    out[obase + 1536] = fmaxf(acc2[nt][3] + bv1.w, 0.f);
  }
}

extern "C" void kernel_launch(void* const* d_in, const int* in_sizes, int n_in,
                              void* d_out, int out_size, void* d_ws, size_t ws_size,
                              hipStream_t stream) {
  const float* x  = (const float*)d_in[0];
  const float* w0 = (const float*)d_in[1];
  const float* b0 = (const float*)d_in[2];
  const float* w1 = (const float*)d_in[3];
  const float* b1 = (const float*)d_in[4];
  char* wsb = (char*)d_ws;
  float* out = (float*)d_out;

  prep_fused_weights<<<80, 256, 0, stream>>>(w0, b0, w1, b1, wsb);
  conv_fused<<<dim3(16, 64), 448, 0, stream>>>(x, wsb, out);
}